// Round 1
// baseline (18180.315 us; speedup 1.0000x reference)
//
#include <hip/hip_runtime.h>

// Furthest Point Sampling, B=8, C=3, N=65536, NUM_POINTS=1024.
// Reference: seed idx 0; 1023 steps of {dists = min(dists, ||p - q||^2); next = first-argmax(dists)}.
// Then gather points[b, :, idx] -> out (B,3,1024) float32.
//
// Layout notes:
//  - input points is channels-first (B,3,N): x/y/z planes are each contiguous -> perfect coalescing.
//  - one block per batch (8 blocks, 1024 threads). Each thread owns 64 points (16 float4 groups),
//    min-dists live in registers (64 VGPRs). Points re-streamed from L2 every iteration
//    (768 KB/batch, resident in the batch's XCD L2).
//  - exact-match math: __fmul_rn/__fadd_rn to forbid FMA contraction (reference sums squares
//    without fused ops); argmax tie-break = smallest index (jnp.argmax first-occurrence).

namespace {

constexpr int kN = 65536;
constexpr int kNP = 1024;
constexpr int kThreads = 1024;
constexpr int kGroups = 16;  // float4 groups per thread: 16*4 = 64 points/thread

__global__ __launch_bounds__(kThreads) void fps_kernel(const float* __restrict__ pts,
                                                       float* __restrict__ out) {
  const int b = blockIdx.x;
  const int tid = threadIdx.x;
  const float* __restrict__ xb = pts + (size_t)b * 3 * kN;
  const float* __restrict__ yb = xb + kN;
  const float* __restrict__ zb = xb + 2 * kN;

  __shared__ int s_idx[kNP];
  __shared__ float s_rd[16];
  __shared__ int s_ri[16];
  __shared__ int s_best;

  float dist[kGroups][4];
#pragma unroll
  for (int k = 0; k < kGroups; ++k) {
#pragma unroll
    for (int j = 0; j < 4; ++j) dist[k][j] = 1e10f;
  }

  // Seed: index 0.
  float qx = xb[0], qy = yb[0], qz = zb[0];
  if (tid == 0) s_idx[0] = 0;

  const int lane = tid & 63;
  const int wave = tid >> 6;
  const int base0 = tid * 4;

  for (int it = 1; it < kNP; ++it) {
    float best_d = -1.0f;
    int best_i = 0;

#pragma unroll
    for (int k = 0; k < kGroups; ++k) {
      const int base = k * (kThreads * 4) + base0;
      const float4 px = *reinterpret_cast<const float4*>(xb + base);
      const float4 py = *reinterpret_cast<const float4*>(yb + base);
      const float4 pz = *reinterpret_cast<const float4*>(zb + base);
      const float pxe[4] = {px.x, px.y, px.z, px.w};
      const float pye[4] = {py.x, py.y, py.z, py.w};
      const float pze[4] = {pz.x, pz.y, pz.z, pz.w};
#pragma unroll
      for (int j = 0; j < 4; ++j) {
        const float dx = pxe[j] - qx;
        const float dy = pye[j] - qy;
        const float dz = pze[j] - qz;
        // Exact IEEE ops, no contraction: ((dx*dx + dy*dy) + dz*dz), matching numpy.
        const float ss =
            __fadd_rn(__fadd_rn(__fmul_rn(dx, dx), __fmul_rn(dy, dy)), __fmul_rn(dz, dz));
        const float nd = fminf(dist[k][j], ss);
        dist[k][j] = nd;
        // Strict '>' keeps the earliest index; per-thread scan is ascending in index.
        if (nd > best_d) {
          best_d = nd;
          best_i = base + j;
        }
      }
    }

    // Wave-level argmax reduction (64 lanes), tie -> smaller index.
#pragma unroll
    for (int off = 32; off > 0; off >>= 1) {
      const float od = __shfl_xor(best_d, off, 64);
      const int oi = __shfl_xor(best_i, off, 64);
      if (od > best_d || (od == best_d && oi < best_i)) {
        best_d = od;
        best_i = oi;
      }
    }

    if (lane == 0) {
      s_rd[wave] = best_d;
      s_ri[wave] = best_i;
    }
    __syncthreads();

    if (wave == 0) {
      float d = (lane < 16) ? s_rd[lane] : -1.0f;
      int i = (lane < 16) ? s_ri[lane] : 0x7fffffff;
#pragma unroll
      for (int off = 8; off > 0; off >>= 1) {
        const float od = __shfl_xor(d, off, 64);
        const int oi = __shfl_xor(i, off, 64);
        if (od > d || (od == d && oi < i)) {
          d = od;
          i = oi;
        }
      }
      if (lane == 0) {
        s_best = i;
        s_idx[it] = i;
      }
    }
    __syncthreads();

    const int bi = s_best;
    // Broadcast load: all threads hit the same 3 addresses (L1-served).
    qx = xb[bi];
    qy = yb[bi];
    qz = zb[bi];
  }

  // Gather: out[b][c][j] = points[b][c][idx[j]] ; kThreads == kNP so j == tid.
  // (All waves passed the final barrier, so s_idx is complete and visible.)
  const int id = s_idx[tid];
  float* __restrict__ ob = out + (size_t)b * 3 * kNP;
  ob[tid] = xb[id];
  ob[kNP + tid] = yb[id];
  ob[2 * kNP + tid] = zb[id];
}

}  // namespace

extern "C" void kernel_launch(void* const* d_in, const int* in_sizes, int n_in,
                              void* d_out, int out_size, void* d_ws, size_t ws_size,
                              hipStream_t stream) {
  (void)in_sizes;
  (void)n_in;
  (void)d_ws;
  (void)ws_size;
  (void)out_size;
  const float* pts = (const float*)d_in[0];
  float* out = (float*)d_out;
  fps_kernel<<<dim3(8), dim3(kThreads), 0, stream>>>(pts, out);
}

// Round 2
// 11293.035 us; speedup vs baseline: 1.6099x; 1.6099x over previous
//
#include <hip/hip_runtime.h>

// Furthest Point Sampling, B=8, C=3, N=65536, NUM_POINTS=1024.
//
// Multi-block-per-batch design: 32 blocks x 256 threads per batch (256 blocks total,
// 4 waves each -> 1024 of 8192 wave slots; all blocks co-resident by capacity).
// Each block holds its 2048 points' coords in REGISTERS (8 pts/thread), so the
// per-iteration distance update touches no memory. Global argmax per iteration via
// one packed-u64 atomicMax per block + arrival counter + acquire spin.
//
// Key packing: (float_bits(d) << 32) | (0xFFFFFFFF - idx). d >= 0 so float bits are
// monotone; max key = max dist, tie -> smaller index == jnp.argmax first-occurrence.
// Distance math: __fmul_rn/__fadd_rn (no FMA contraction) to bit-match numpy.

namespace {

constexpr int kB = 8;
constexpr int kN = 65536;
constexpr int kNP = 1024;
constexpr int kPB = 32;                // blocks per batch
constexpr int kThreads = 256;
constexpr int kPPB = kN / kPB;         // 2048 points per block
constexpr int kPPT = kPPB / kThreads;  // 8 points per thread
constexpr int kGrp = kPPT / 4;         // 2 float4 groups
constexpr int kWaves = kThreads / 64;

__device__ __forceinline__ unsigned long long pack_key(float d, int idx) {
  return ((unsigned long long)__float_as_uint(d) << 32) |
         (unsigned long long)(0xFFFFFFFFu - (unsigned)idx);
}

__global__ __launch_bounds__(kThreads) void fps_kernel(const float* __restrict__ pts,
                                                       float* __restrict__ out,
                                                       unsigned long long* __restrict__ bestkey,
                                                       unsigned* __restrict__ arrive) {
  const int batch = blockIdx.x & 7;   // round-robin => one XCD per batch
  const int slice = blockIdx.x >> 3;  // 0..31
  const int tid = threadIdx.x;
  const int lane = tid & 63;
  const int wave = tid >> 6;

  const float* __restrict__ xb = pts + (size_t)batch * 3 * kN;
  const float* __restrict__ yb = xb + kN;
  const float* __restrict__ zb = xb + 2 * kN;

  unsigned long long* __restrict__ bk = bestkey + batch * kNP;
  unsigned* __restrict__ ar = arrive + batch * kNP;

  __shared__ unsigned long long s_wkey[kWaves];
  __shared__ int s_hist[kNP];

  // Register-resident coords: thread t owns indices sbase + g*1024 + t*4 + j.
  const int sbase = slice * kPPB;
  float px[kPPT], py[kPPT], pz[kPPT], dist[kPPT];
#pragma unroll
  for (int g = 0; g < kGrp; ++g) {
    const int base = sbase + g * (kThreads * 4) + tid * 4;
    const float4 vx = *reinterpret_cast<const float4*>(xb + base);
    const float4 vy = *reinterpret_cast<const float4*>(yb + base);
    const float4 vz = *reinterpret_cast<const float4*>(zb + base);
    px[g * 4 + 0] = vx.x; px[g * 4 + 1] = vx.y; px[g * 4 + 2] = vx.z; px[g * 4 + 3] = vx.w;
    py[g * 4 + 0] = vy.x; py[g * 4 + 1] = vy.y; py[g * 4 + 2] = vy.z; py[g * 4 + 3] = vy.w;
    pz[g * 4 + 0] = vz.x; pz[g * 4 + 1] = vz.y; pz[g * 4 + 2] = vz.z; pz[g * 4 + 3] = vz.w;
  }
#pragma unroll
  for (int k = 0; k < kPPT; ++k) dist[k] = 1e10f;

  // Seed: index 0 (uniform broadcast load).
  float qx = xb[0], qy = yb[0], qz = zb[0];

  for (int it = 1; it < kNP; ++it) {
    // --- update dists + per-thread argmax (ascending index, strict '>') ---
    float bd = -1.0f;
    int bi = 0;
#pragma unroll
    for (int g = 0; g < kGrp; ++g) {
#pragma unroll
      for (int j = 0; j < 4; ++j) {
        const int k = g * 4 + j;
        const float dx = px[k] - qx;
        const float dy = py[k] - qy;
        const float dz = pz[k] - qz;
        const float ss =
            __fadd_rn(__fadd_rn(__fmul_rn(dx, dx), __fmul_rn(dy, dy)), __fmul_rn(dz, dz));
        const float nd = fminf(dist[k], ss);
        dist[k] = nd;
        if (nd > bd) {
          bd = nd;
          bi = sbase + g * (kThreads * 4) + tid * 4 + j;
        }
      }
    }

    // --- in-block reduce on packed keys ---
    unsigned long long key = pack_key(bd, bi);
#pragma unroll
    for (int off = 32; off > 0; off >>= 1) {
      const unsigned long long ok =
          (unsigned long long)__shfl_xor((long long)key, off, 64);
      key = ok > key ? ok : key;
    }
    if (lane == 0) s_wkey[wave] = key;
    __syncthreads();

    if (tid == 0) {
      unsigned long long k0 = s_wkey[0];
#pragma unroll
      for (int w = 1; w < kWaves; ++w) {
        const unsigned long long kw = s_wkey[w];
        k0 = kw > k0 ? kw : k0;
      }
      // --- cross-block reduce: atomicMax then release-arrive ---
      atomicMax(&bk[it], k0);
      __threadfence();
      __hip_atomic_fetch_add(&ar[it], 1u, __ATOMIC_RELEASE, __HIP_MEMORY_SCOPE_AGENT);
      // --- spin until all kPB blocks of this batch arrived ---
      while (__hip_atomic_load(&ar[it], __ATOMIC_ACQUIRE, __HIP_MEMORY_SCOPE_AGENT) < kPB) {
        __builtin_amdgcn_s_sleep(1);
      }
      const unsigned long long win =
          __hip_atomic_load(&bk[it], __ATOMIC_RELAXED, __HIP_MEMORY_SCOPE_AGENT);
      s_hist[it] = (int)(0xFFFFFFFFu - (unsigned)(win & 0xFFFFFFFFull));
    }
    __syncthreads();

    const int wi = s_hist[it];
    // Uniform broadcast load of the new query point (L1/L2 hit).
    qx = xb[wi];
    qy = yb[wi];
    qz = zb[wi];
  }

  // --- gather: out[b][c][j] = points[b][c][idx_j]; slice-0 block per batch ---
  if (slice == 0) {
    float* __restrict__ ob = out + (size_t)batch * 3 * kNP;
    for (int j = tid; j < kNP; j += kThreads) {
      const int id = (j == 0) ? 0 : s_hist[j];
      ob[j] = xb[id];
      ob[kNP + j] = yb[id];
      ob[2 * kNP + j] = zb[id];
    }
  }
}

}  // namespace

extern "C" void kernel_launch(void* const* d_in, const int* in_sizes, int n_in,
                              void* d_out, int out_size, void* d_ws, size_t ws_size,
                              hipStream_t stream) {
  (void)in_sizes;
  (void)n_in;
  (void)out_size;
  (void)ws_size;
  const float* pts = (const float*)d_in[0];
  float* out = (float*)d_out;
  unsigned long long* bestkey = (unsigned long long*)d_ws;
  unsigned* arrive = (unsigned*)((char*)d_ws + (size_t)kB * kNP * sizeof(unsigned long long));
  const size_t clear_bytes = (size_t)kB * kNP * (sizeof(unsigned long long) + sizeof(unsigned));
  hipMemsetAsync(d_ws, 0, clear_bytes, stream);
  fps_kernel<<<dim3(kB * kPB), dim3(kThreads), 0, stream>>>(pts, out, bestkey, arrive);
}

// Round 3
// 1812.965 us; speedup vs baseline: 10.0279x; 6.2290x over previous
//
#include <hip/hip_runtime.h>

// Furthest Point Sampling, B=8, C=3, N=65536, NUM_POINTS=1024.
//
// R3 design: 16 blocks x 512 threads per batch (128 blocks total). Each block holds
// its 4096 points' coords in REGISTERS (8 pts/thread). Per iteration:
//   1. register distance update + in-block argmax (shuffle butterfly + LDS),
//   2. block PUBLISHES its packed key to its own 8B slot (relaxed agent atomic store
//      -- no RMW, no same-address serialization; 16 slots = one 128B line),
//   3. wave 0 polls all 16 slots in ONE load round (lane&15), waits all nonzero,
//      reduces the winner locally via 4-step butterfly.
// No atomicMax / arrive counter / fences on the critical path (R2's 11 us/iter was
// 64 serialized far RMWs to two hot addresses).
//
// Key packing: (float_bits(d) << 32) | (0xFFFFFFFF - idx). d >= 0 so float bits are
// monotone; max key = max dist, tie -> smaller index == jnp.argmax first-occurrence.
// Key is always nonzero (idx <= 65535 -> low word >= 0xFFFF0000), so 0 == "not posted".
// Distance math: __fmul_rn/__fadd_rn (no FMA contraction) to bit-match numpy.

namespace {

constexpr int kB = 8;
constexpr int kN = 65536;
constexpr int kNP = 1024;
constexpr int kPB = 16;                       // blocks per batch
constexpr int kThreads = 512;
constexpr int kPPT = kN / (kPB * kThreads);   // 8 points per thread
constexpr int kGrp = kPPT / 4;                // 2 float4 groups
constexpr int kWaves = kThreads / 64;         // 8

__device__ __forceinline__ unsigned long long pack_key(float d, int idx) {
  return ((unsigned long long)__float_as_uint(d) << 32) |
         (unsigned long long)(0xFFFFFFFFu - (unsigned)idx);
}

__device__ __forceinline__ unsigned long long u64max(unsigned long long a,
                                                     unsigned long long b) {
  return a > b ? a : b;
}

__global__ __launch_bounds__(kThreads) void fps_kernel(const float* __restrict__ pts,
                                                       float* __restrict__ out,
                                                       unsigned long long* __restrict__ slots) {
  const int batch = blockIdx.x & 7;   // round-robin => batch's blocks share an XCD (perf heuristic)
  const int slice = blockIdx.x >> 3;  // 0..15
  const int tid = threadIdx.x;
  const int lane = tid & 63;
  const int wave = tid >> 6;

  const float* __restrict__ xb = pts + (size_t)batch * 3 * kN;
  const float* __restrict__ yb = xb + kN;
  const float* __restrict__ zb = xb + 2 * kN;

  __shared__ unsigned long long s_wkey[kWaves];
  __shared__ int s_hist[kNP];
  __shared__ int s_win;

  // Register-resident coords: block owns [slice*4096, slice*4096+4096).
  const int sbase = slice * (kThreads * kPPT);
  float px[kPPT], py[kPPT], pz[kPPT], dist[kPPT];
#pragma unroll
  for (int g = 0; g < kGrp; ++g) {
    const int base = sbase + g * (kThreads * 4) + tid * 4;
    const float4 vx = *reinterpret_cast<const float4*>(xb + base);
    const float4 vy = *reinterpret_cast<const float4*>(yb + base);
    const float4 vz = *reinterpret_cast<const float4*>(zb + base);
    px[g * 4 + 0] = vx.x; px[g * 4 + 1] = vx.y; px[g * 4 + 2] = vx.z; px[g * 4 + 3] = vx.w;
    py[g * 4 + 0] = vy.x; py[g * 4 + 1] = vy.y; py[g * 4 + 2] = vy.z; py[g * 4 + 3] = vy.w;
    pz[g * 4 + 0] = vz.x; pz[g * 4 + 1] = vz.y; pz[g * 4 + 2] = vz.z; pz[g * 4 + 3] = vz.w;
  }
#pragma unroll
  for (int k = 0; k < kPPT; ++k) dist[k] = 1e10f;

  // Seed: index 0 (uniform broadcast load).
  float qx = xb[0], qy = yb[0], qz = zb[0];

  for (int it = 1; it < kNP; ++it) {
    // --- update dists + per-thread argmax (ascending index, strict '>') ---
    float bd = -1.0f;
    int bi = 0;
#pragma unroll
    for (int g = 0; g < kGrp; ++g) {
#pragma unroll
      for (int j = 0; j < 4; ++j) {
        const int k = g * 4 + j;
        const float dx = px[k] - qx;
        const float dy = py[k] - qy;
        const float dz = pz[k] - qz;
        const float ss =
            __fadd_rn(__fadd_rn(__fmul_rn(dx, dx), __fmul_rn(dy, dy)), __fmul_rn(dz, dz));
        const float nd = fminf(dist[k], ss);
        dist[k] = nd;
        if (nd > bd) {
          bd = nd;
          bi = sbase + g * (kThreads * 4) + tid * 4 + j;
        }
      }
    }

    // --- wave butterfly on packed keys ---
    unsigned long long key = pack_key(bd, bi);
#pragma unroll
    for (int off = 32; off > 0; off >>= 1) {
      key = u64max(key, (unsigned long long)__shfl_xor((long long)key, off, 64));
    }
    if (lane == 0) s_wkey[wave] = key;
    __syncthreads();

    // --- wave 0: block reduce -> publish -> poll peers -> global winner ---
    if (wave == 0) {
      unsigned long long k = s_wkey[lane & (kWaves - 1)];
#pragma unroll
      for (int off = kWaves / 2; off > 0; off >>= 1) {
        k = u64max(k, (unsigned long long)__shfl_xor((long long)k, off, 64));
      }
      unsigned long long* slot_base = slots + ((size_t)batch * kNP + it) * kPB;
      if (lane == 0) {
        // Publish: plain agent-scope atomic store to our own slot. No RMW.
        __hip_atomic_store(slot_base + slice, k, __ATOMIC_RELAXED, __HIP_MEMORY_SCOPE_AGENT);
      }
      // Poll all 16 slots in one load round (4x redundant over 64 lanes; one 128B line).
      unsigned long long pk;
      do {
        pk = __hip_atomic_load(slot_base + (lane & (kPB - 1)), __ATOMIC_RELAXED,
                               __HIP_MEMORY_SCOPE_AGENT);
      } while (!__all(pk != 0));
#pragma unroll
      for (int off = kPB / 2; off > 0; off >>= 1) {
        pk = u64max(pk, (unsigned long long)__shfl_xor((long long)pk, off, 64));
      }
      if (lane == 0) {
        const int wi = (int)(0xFFFFFFFFu - (unsigned)(pk & 0xFFFFFFFFull));
        s_win = wi;
        s_hist[it] = wi;
      }
    }
    __syncthreads();

    const int wi = s_win;
    // Uniform broadcast load of the new query point (read-only data, L2 hit).
    qx = xb[wi];
    qy = yb[wi];
    qz = zb[wi];
  }

  // --- gather: out[b][c][j] = points[b][c][idx_j]; slice-0 block per batch ---
  if (slice == 0) {
    float* __restrict__ ob = out + (size_t)batch * 3 * kNP;
    for (int j = tid; j < kNP; j += kThreads) {
      const int id = (j == 0) ? 0 : s_hist[j];
      ob[j] = xb[id];
      ob[kNP + j] = yb[id];
      ob[2 * kNP + j] = zb[id];
    }
  }
}

}  // namespace

extern "C" void kernel_launch(void* const* d_in, const int* in_sizes, int n_in,
                              void* d_out, int out_size, void* d_ws, size_t ws_size,
                              hipStream_t stream) {
  (void)in_sizes;
  (void)n_in;
  (void)out_size;
  (void)ws_size;
  const float* pts = (const float*)d_in[0];
  float* out = (float*)d_out;
  unsigned long long* slots = (unsigned long long*)d_ws;
  // 8 batches x 1024 iters x 16 slots x 8B = 1 MB; harness poisons ws each launch.
  const size_t clear_bytes = (size_t)kB * kNP * kPB * sizeof(unsigned long long);
  hipMemsetAsync(d_ws, 0, clear_bytes, stream);
  fps_kernel<<<dim3(kB * kPB), dim3(kThreads), 0, stream>>>(pts, out, slots);
}